// Round 1
// baseline (324.079 us; speedup 1.0000x reference)
//
#include <hip/hip_runtime.h>

typedef float f32x4 __attribute__((ext_vector_type(4)));
typedef __bf16 bf16x8 __attribute__((ext_vector_type(8)));

__device__ __forceinline__ unsigned short f2bf(float f) {
  unsigned int u = __float_as_uint(f);
  u += 0x7FFFu + ((u >> 16) & 1u);   // round-to-nearest-even
  return (unsigned short)(u >> 16);
}
__device__ __forceinline__ unsigned int pk2(float a, float b) {
  return (unsigned int)f2bf(a) | ((unsigned int)f2bf(b) << 16);
}

// ---- Kernel 0: weights -> bf16, transposed concat Wt[n][k] (k=0..255), bias sum ----
__global__ void k_prep(const float* __restrict__ Ws, const float* __restrict__ Wn,
                       const float* __restrict__ bs, const float* __restrict__ bn,
                       unsigned short* __restrict__ wt, float* __restrict__ bias) {
  int idx = blockIdx.x * 256 + threadIdx.x;   // 0..32767
  int n = idx >> 8, k = idx & 255;
  float v = (k < 128) ? Ws[k * 128 + n] : Wn[(k - 128) * 128 + n];
  wt[n * 256 + k] = f2bf(v);
  if (idx < 128) bias[idx] = bs[idx] + bn[idx];
}

// ---- Kernel 1: segmented cumulative mean of src_feat over dst buckets ----
// One 64-lane wave per R-edge range; lane owns 2 columns (float2, coalesced 512B/row).
template<bool BF16H>
__global__ __launch_bounds__(256) void k_cummean(
    const float* __restrict__ src, const int* __restrict__ dst,
    unsigned short* __restrict__ hbf, float* __restrict__ hf32,
    int E, int ngroups, int R)
{
  int g = blockIdx.x * 4 + (threadIdx.x >> 6);
  if (g >= ngroups) return;
  int lane = threadIdx.x & 63;
  long e0 = (long)g * R;
  long e1 = e0 + R; if (e1 > E) e1 = E;

  // find start of the bucket containing e0 (dst is sorted; buckets are tiny, L2-cached)
  int d0 = dst[e0];
  long s = e0;
  while (s > 0 && dst[s - 1] == d0) --s;

  float ax = 0.f, ay = 0.f;
  for (long e = s; e < e0; ++e) {           // partial-bucket base sum
    float2 v = *(const float2*)(src + e * 128 + lane * 2);
    ax += v.x; ay += v.y;
  }
  int pos = (int)(e0 - s);
  int prevd = d0;
  #pragma unroll 4
  for (long e = e0; e < e1; ++e) {
    int d = dst[e];
    if (d != prevd) { ax = 0.f; ay = 0.f; pos = 0; prevd = d; }
    float2 v = *(const float2*)(src + e * 128 + lane * 2);
    ax += v.x; ay += v.y;
    float inv = 1.0f / (float)(pos + 1);
    if (BF16H) {
      *(unsigned int*)(hbf + e * 128 + lane * 2) = pk2(ax * inv, ay * inv);
    } else {
      float2 o; o.x = ax * inv; o.y = ay * inv;
      *(float2*)(hf32 + e * 128 + lane * 2) = o;
    }
    ++pos;
  }
}

// ---- Kernel 2: out[tile] = [bf16(dst_feat) | h] @ Wt^T + bias  (K=256 bf16 MFMA) ----
// 128-row tiles, 4 waves, each wave 32 rows x 128 cols. A in LDS (XOR-swizzled),
// B fragments straight from L2-resident Wt.
template<bool BF16H>
__global__ __launch_bounds__(256, 2) void k_gemm(
    const float* __restrict__ dstf, const unsigned short* __restrict__ hbf,
    const float* __restrict__ hf32, const unsigned short* __restrict__ wt,
    const float* __restrict__ bias, float* __restrict__ out, int E)
{
  __shared__ __align__(16) unsigned char smem[128 * 512];  // A_cat[128 rows][256 k] bf16
  const int tid = threadIdx.x;
  const int lane = tid & 63, wid = tid >> 6;
  const long e0 = (long)blockIdx.x * 128;

  // ---- stage A tile ----
  {
    const int r = tid >> 1, hh = tid & 1;           // 2 threads per row
    long er = e0 + r; long emax = (long)E - 1; if (er > emax) er = emax; // tail clamp stays in-tile
    unsigned char* rowbase = smem + r * 512;
    const int swz = (r & 7) << 4;

    const float* p = dstf + er * 128 + hh * 64;     // k in [0,128): bf16(dst_feat)
    #pragma unroll
    for (int j = 0; j < 8; ++j) {
      float4 v0 = *(const float4*)(p + j * 8);
      float4 v1 = *(const float4*)(p + j * 8 + 4);
      int4 w; w.x = pk2(v0.x, v0.y); w.y = pk2(v0.z, v0.w);
      w.z = pk2(v1.x, v1.y); w.w = pk2(v1.z, v1.w);
      int off = hh * 128 + j * 16;
      *(int4*)(rowbase + (off ^ swz)) = w;
    }
    if (BF16H) {
      const unsigned short* q = hbf + er * 128 + hh * 64;   // k in [128,256): h (bf16)
      #pragma unroll
      for (int j = 0; j < 8; ++j) {
        int4 v = *(const int4*)(q + j * 8);
        int off = 256 + hh * 128 + j * 16;
        *(int4*)(rowbase + (off ^ swz)) = v;
      }
    } else {
      const float* q = hf32 + er * 128 + hh * 64;           // h (f32, lives in d_out)
      #pragma unroll
      for (int j = 0; j < 8; ++j) {
        float4 v0 = *(const float4*)(q + j * 8);
        float4 v1 = *(const float4*)(q + j * 8 + 4);
        int4 w; w.x = pk2(v0.x, v0.y); w.y = pk2(v0.z, v0.w);
        w.z = pk2(v1.x, v1.y); w.w = pk2(v1.z, v1.w);
        int off = 256 + hh * 128 + j * 16;
        *(int4*)(rowbase + (off ^ swz)) = w;
      }
    }
  }
  __syncthreads();

  f32x4 acc[2][8];
  #pragma unroll
  for (int rt = 0; rt < 2; ++rt)
    #pragma unroll
    for (int ct = 0; ct < 8; ++ct) acc[rt][ct] = (f32x4){0.f, 0.f, 0.f, 0.f};

  const int l15 = lane & 15, lg = lane >> 4;
  float bcol[8];
  #pragma unroll
  for (int ct = 0; ct < 8; ++ct) bcol[ct] = bias[ct * 16 + l15];

  #pragma unroll
  for (int kt = 0; kt < 8; ++kt) {
    bf16x8 a[2];
    #pragma unroll
    for (int rt = 0; rt < 2; ++rt) {
      int row = wid * 32 + rt * 16 + l15;
      int kb = (kt * 32 + lg * 8) * 2;
      a[rt] = *(const bf16x8*)(smem + row * 512 + (kb ^ ((row & 7) << 4)));
    }
    bf16x8 b[8];
    #pragma unroll
    for (int ct = 0; ct < 8; ++ct)
      b[ct] = *(const bf16x8*)(wt + (ct * 16 + l15) * 256 + kt * 32 + lg * 8);
    #pragma unroll
    for (int rt = 0; rt < 2; ++rt)
      #pragma unroll
      for (int ct = 0; ct < 8; ++ct)
        acc[rt][ct] = __builtin_amdgcn_mfma_f32_16x16x32_bf16(a[rt], b[ct], acc[rt][ct], 0, 0, 0);
  }

  // ---- epilogue: D layout col=lane&15, row=(lane>>4)*4+i ----
  #pragma unroll
  for (int rt = 0; rt < 2; ++rt) {
    #pragma unroll
    for (int i = 0; i < 4; ++i) {
      long row = e0 + wid * 32 + rt * 16 + lg * 4 + i;
      if (row < E) {
        float* op = out + row * 128 + l15;
        #pragma unroll
        for (int ct = 0; ct < 8; ++ct) op[ct * 16] = acc[rt][ct][i] + bcol[ct];
      }
    }
  }
}

extern "C" void kernel_launch(void* const* d_in, const int* in_sizes, int n_in,
                              void* d_out, int out_size, void* d_ws, size_t ws_size,
                              hipStream_t stream) {
  const float* src_feat = (const float*)d_in[0];
  const float* dst_feat = (const float*)d_in[1];
  const int*   dst      = (const int*)d_in[2];
  const float* W_self   = (const float*)d_in[3];
  const float* b_self   = (const float*)d_in[4];
  const float* W_neigh  = (const float*)d_in[5];
  const float* b_neigh  = (const float*)d_in[6];
  float* out = (float*)d_out;
  const int E = in_sizes[2];

  unsigned short* wt   = (unsigned short*)d_ws;                    // 64KB: Wt[n][k] bf16
  float*          bias = (float*)((char*)d_ws + 65536);            // 512B
  unsigned short* hbf  = (unsigned short*)((char*)d_ws + 131072);  // E*128 bf16
  size_t need = 131072 + (size_t)E * 256;
  bool bf16h = ws_size >= need;   // fallback: h as f32 in d_out (tile-safe overwrite)

  k_prep<<<128, 256, 0, stream>>>(W_self, W_neigh, b_self, b_neigh, wt, bias);

  const int R = 64;
  int ngroups = (E + R - 1) / R;
  int blocks1 = (ngroups + 3) / 4;
  if (bf16h)
    k_cummean<true ><<<blocks1, 256, 0, stream>>>(src_feat, dst, hbf, out, E, ngroups, R);
  else
    k_cummean<false><<<blocks1, 256, 0, stream>>>(src_feat, dst, hbf, out, E, ngroups, R);

  int blocks2 = (E + 127) / 128;
  if (bf16h)
    k_gemm<true ><<<blocks2, 256, 0, stream>>>(dst_feat, hbf, out, wt, bias, out, E);
  else
    k_gemm<false><<<blocks2, 256, 0, stream>>>(dst_feat, hbf, out, wt, bias, out, E);
}

// Round 2
// 286.521 us; speedup vs baseline: 1.1311x; 1.1311x over previous
//
#include <hip/hip_runtime.h>

typedef float f32x4 __attribute__((ext_vector_type(4)));
typedef __bf16 bf16x8 __attribute__((ext_vector_type(8)));

__device__ __forceinline__ unsigned short f2bf(float f) {
  unsigned int u = __float_as_uint(f);
  u += 0x7FFFu + ((u >> 16) & 1u);   // round-to-nearest-even
  return (unsigned short)(u >> 16);
}
__device__ __forceinline__ unsigned int pk2(float a, float b) {
  return (unsigned int)f2bf(a) | ((unsigned int)f2bf(b) << 16);
}

// ---- Kernel 0: weights -> bf16, transposed concat Wt[n][k] (k=0..255), bias sum ----
__global__ void k_prep(const float* __restrict__ Ws, const float* __restrict__ Wn,
                       const float* __restrict__ bs, const float* __restrict__ bn,
                       unsigned short* __restrict__ wt, float* __restrict__ bias) {
  int idx = blockIdx.x * 256 + threadIdx.x;   // 0..32767
  int n = idx >> 8, k = idx & 255;
  float v = (k < 128) ? Ws[k * 128 + n] : Wn[(k - 128) * 128 + n];
  wt[n * 256 + k] = f2bf(v);
  if (idx < 128) bias[idx] = bs[idx] + bn[idx];
}

// ---- Fused kernel: cummean (LDS-local) + dual GEMM, barrier-free ----
// One wave owns 32 output rows. Phase 1: segmented cummean of src rows into a
// private 8KB LDS slab (bf16, XOR-swizzled). Phase 2: K=256 MFMA where
// kt 0..3 = dst_feat straight from global (inline f32->bf16), kt 4..7 = h from
// LDS, B from L2-resident wt. No __syncthreads anywhere.
__global__ __launch_bounds__(256) void k_fused(
    const float* __restrict__ src, const float* __restrict__ dstf,
    const int* __restrict__ dst, const unsigned short* __restrict__ wt,
    const float* __restrict__ bias, float* __restrict__ out, int E)
{
  __shared__ __align__(16) unsigned char hsm[4][32 * 256];
  const int lane = threadIdx.x & 63, wid = threadIdx.x >> 6;
  const int l15 = lane & 15, lg = lane >> 4;
  const long e0 = (long)blockIdx.x * 128 + wid * 32;
  if (e0 >= E) return;                       // no barrier in kernel -> safe
  unsigned char* hrow = hsm[wid];

  // ---- phase 1: cummean of rows [e0, min(e0+32,E)) into LDS ----
  {
    const int c = lane * 2;                  // this lane's column pair
    const int cb = lane * 4;                 // its byte offset in a 256B row
    int d0 = dst[e0];
    long s = e0;
    while (s > 0 && dst[s - 1] == d0) --s;   // bucket start (avg ~4.5 back)
    float ax = 0.f, ay = 0.f;
    for (long e = s; e < e0; ++e) {          // partial-bucket base sum
      float2 v = *(const float2*)(src + e * 128 + c);
      ax += v.x; ay += v.y;
    }
    int pos = (int)(e0 - s);
    int prevd = d0;
    long e1 = e0 + 32; if (e1 > E) e1 = E;
    #pragma unroll 8
    for (long e = e0; e < e1; ++e) {
      int d = dst[e];                        // wave-uniform broadcast load
      if (d != prevd) { ax = 0.f; ay = 0.f; pos = 0; prevd = d; }
      float2 v = *(const float2*)(src + e * 128 + c);
      ax += v.x; ay += v.y;
      float inv = 1.0f / (float)(pos + 1);
      int r = (int)(e - e0);
      *(unsigned int*)(hrow + r * 256 + (cb ^ ((r & 7) << 4))) = pk2(ax * inv, ay * inv);
      ++pos;
    }
    // tail rows (if e1<e0+32) stay garbage in LDS; their MFMA output rows are
    // masked at the store (garbage A row r only affects D row r).
  }

  // wave reads only its OWN LDS rows -> no __syncthreads; just drain LDS queue
  asm volatile("s_waitcnt lgkmcnt(0)" ::: "memory");

  // ---- phase 2: 32 rows x 128 cols, K=256 ----
  f32x4 acc[2][8];
  #pragma unroll
  for (int rt = 0; rt < 2; ++rt)
    #pragma unroll
    for (int ct = 0; ct < 8; ++ct) acc[rt][ct] = (f32x4){0.f, 0.f, 0.f, 0.f};

  float bcol[8];
  #pragma unroll
  for (int ct = 0; ct < 8; ++ct) bcol[ct] = bias[ct * 16 + l15];

  #pragma unroll
  for (int kt = 0; kt < 8; ++kt) {
    bf16x8 a[2];
    #pragma unroll
    for (int rt = 0; rt < 2; ++rt) {
      if (kt < 4) {                          // k in [0,128): dst_feat from global
        long row = e0 + rt * 16 + l15;
        long emax = (long)E - 1; if (row > emax) row = emax;
        const float* p = dstf + row * 128 + kt * 32 + lg * 8;
        float4 v0 = *(const float4*)p;
        float4 v1 = *(const float4*)(p + 4);
        union { unsigned int u[4]; bf16x8 v; } cv;
        cv.u[0] = pk2(v0.x, v0.y); cv.u[1] = pk2(v0.z, v0.w);
        cv.u[2] = pk2(v1.x, v1.y); cv.u[3] = pk2(v1.z, v1.w);
        a[rt] = cv.v;
      } else {                               // k in [128,256): h from LDS
        int r = rt * 16 + l15;
        int kb = (kt - 4) * 64 + lg * 16;
        a[rt] = *(const bf16x8*)(hrow + r * 256 + (kb ^ ((r & 7) << 4)));
      }
    }
    bf16x8 b[8];
    #pragma unroll
    for (int ct = 0; ct < 8; ++ct)
      b[ct] = *(const bf16x8*)(wt + (ct * 16 + l15) * 256 + kt * 32 + lg * 8);
    #pragma unroll
    for (int rt = 0; rt < 2; ++rt)
      #pragma unroll
      for (int ct = 0; ct < 8; ++ct)
        acc[rt][ct] = __builtin_amdgcn_mfma_f32_16x16x32_bf16(a[rt], b[ct], acc[rt][ct], 0, 0, 0);
  }

  // ---- epilogue: D layout col=lane&15, row=(lane>>4)*4+i ----
  #pragma unroll
  for (int rt = 0; rt < 2; ++rt) {
    #pragma unroll
    for (int i = 0; i < 4; ++i) {
      long row = e0 + rt * 16 + lg * 4 + i;
      if (row < E) {
        float* op = out + row * 128 + l15;
        #pragma unroll
        for (int ct = 0; ct < 8; ++ct) op[ct * 16] = acc[rt][ct][i] + bcol[ct];
      }
    }
  }
}

extern "C" void kernel_launch(void* const* d_in, const int* in_sizes, int n_in,
                              void* d_out, int out_size, void* d_ws, size_t ws_size,
                              hipStream_t stream) {
  const float* src_feat = (const float*)d_in[0];
  const float* dst_feat = (const float*)d_in[1];
  const int*   dst      = (const int*)d_in[2];
  const float* W_self   = (const float*)d_in[3];
  const float* b_self   = (const float*)d_in[4];
  const float* W_neigh  = (const float*)d_in[5];
  const float* b_neigh  = (const float*)d_in[6];
  float* out = (float*)d_out;
  const int E = in_sizes[2];

  unsigned short* wt   = (unsigned short*)d_ws;           // 64KB: Wt[n][k] bf16
  float*          bias = (float*)((char*)d_ws + 65536);   // 512B

  k_prep<<<128, 256, 0, stream>>>(W_self, W_neigh, b_self, b_neigh, wt, bias);

  int blocks = (E + 127) / 128;
  k_fused<<<blocks, 256, 0, stream>>>(src_feat, dst_feat, dst, wt, bias, out, E);
}

// Round 3
// 232.725 us; speedup vs baseline: 1.3925x; 1.2312x over previous
//
#include <hip/hip_runtime.h>

typedef float f32x4 __attribute__((ext_vector_type(4)));
typedef __bf16 bf16x8 __attribute__((ext_vector_type(8)));

__device__ __forceinline__ unsigned short f2bf(float f) {
  unsigned int u = __float_as_uint(f);
  u += 0x7FFFu + ((u >> 16) & 1u);   // round-to-nearest-even
  return (unsigned short)(u >> 16);
}
__device__ __forceinline__ unsigned int pk2(float a, float b) {
  return (unsigned int)f2bf(a) | ((unsigned int)f2bf(b) << 16);
}

// ---- Kernel 0: weights -> bf16, fragment-contiguous layout + bias sum ----
// b-fragment for (kt,ct) is 1KB contiguous: wt[(kt*8+ct)*512 + lane*8 + j]
// where lane=lg*16+l15 maps to (n=ct*16+l15, k=kt*32+lg*8+j).
__global__ void k_prep(const float* __restrict__ Ws, const float* __restrict__ Wn,
                       const float* __restrict__ bs, const float* __restrict__ bn,
                       unsigned short* __restrict__ wt, float* __restrict__ bias) {
  int idx = blockIdx.x * 256 + threadIdx.x;   // 0..32767
  int n = idx >> 8, k = idx & 255;
  float v = (k < 128) ? Ws[k * 128 + n] : Wn[(k - 128) * 128 + n];
  int ct = n >> 4, l15 = n & 15, kt = k >> 5, lg = (k >> 3) & 3, j = k & 7;
  wt[(((kt << 3) | ct) << 9) + (((lg << 4) | l15) << 3) + j] = f2bf(v);
  if (idx < 128) bias[idx] = bs[idx] + bn[idx];
}

// ---- Fused: cummean (LDS-local) + dual GEMM; no barriers; 16 rows/wave ----
__global__ __launch_bounds__(256, 4) void k_fused(
    const float* __restrict__ src, const float* __restrict__ dstf,
    const int* __restrict__ dst, const unsigned short* __restrict__ wt,
    const float* __restrict__ bias, float* __restrict__ out, int E)
{
  __shared__ __align__(16) unsigned char hsm[4][16 * 256];   // 16 KB/block
  const int lane = threadIdx.x & 63, wid = threadIdx.x >> 6;
  const int l15 = lane & 15, lg = lane >> 4;
  const long e0 = (long)blockIdx.x * 64 + wid * 16;
  if (e0 >= E) return;                         // no barrier in kernel -> safe
  unsigned char* hrow = hsm[wid];
  const long emax = (long)E - 1;

  // ---- early issue #1: dst_feat fragments for kt=0,1 (complete under scan) ----
  long arow = e0 + l15; if (arow > emax) arow = emax;
  const float* ap = dstf + arow * 128 + lg * 8;
  float4 af[8];
  #pragma unroll
  for (int kt = 0; kt < 2; ++kt) {
    af[kt * 2]     = *(const float4*)(ap + kt * 32);
    af[kt * 2 + 1] = *(const float4*)(ap + kt * 32 + 4);
  }

  // ---- early issue #2: my 16 dst values (1 load + shuffles) + back-scan ballot ----
  long drow = e0 + l15; if (drow > emax) drow = emax;
  int myd = dst[drow];
  int d0 = __shfl(myd, 0);
  long back = e0 - 1 - lane;
  long backc = back < 0 ? 0 : back;
  int bd = dst[backc];
  unsigned long long m = __ballot((back >= 0) && (bd == d0));
  unsigned long long nm = ~m;
  int L = (nm == 0ull) ? 64 : __builtin_ctzll(nm);
  long s = e0 - L;
  while (s > 0 && dst[s - 1] == d0) --s;       // only if bucket >64 deep (~never)

  // ---- early issue #3: scan-row loads, two 8-row register batches ----
  const int c = lane * 2;
  float2 v0[8], v1[8];
  #pragma unroll
  for (int r = 0; r < 8; ++r) {
    long rr = e0 + r; if (rr > emax) rr = emax;
    v0[r] = *(const float2*)(src + rr * 128 + c);
  }
  #pragma unroll
  for (int r = 0; r < 8; ++r) {
    long rr = e0 + 8 + r; if (rr > emax) rr = emax;
    v1[r] = *(const float2*)(src + rr * 128 + c);
  }

  // ---- partial-bucket base sum (avg ~4.5 rows) ----
  float ax = 0.f, ay = 0.f;
  #pragma unroll 2
  for (long e = s; e < e0; ++e) {
    float2 v = *(const float2*)(src + e * 128 + c);
    ax += v.x; ay += v.y;
  }

  // ---- cummean of my 16 rows into swizzled LDS (bf16) ----
  int pos = (int)(e0 - s);
  int prevd = d0;
  #pragma unroll
  for (int r = 0; r < 16; ++r) {
    int d = __shfl(myd, r);
    if (d != prevd) { ax = 0.f; ay = 0.f; pos = 0; prevd = d; }
    float2 v = (r < 8) ? v0[r] : v1[r - 8];
    ax += v.x; ay += v.y;
    float inv = __builtin_amdgcn_rcpf((float)(pos + 1));
    *(unsigned int*)(hrow + r * 256 + ((lane * 4) ^ ((r & 7) << 4))) = pk2(ax * inv, ay * inv);
    ++pos;
  }

  // drain LDS writes (wave reads only its own rows; DS pipe is in-order)
  asm volatile("s_waitcnt lgkmcnt(0)" ::: "memory");

  // ---- early issue #4: dst_feat fragments kt=2,3 (cover under first MFMAs) ----
  #pragma unroll
  for (int kt = 2; kt < 4; ++kt) {
    af[kt * 2]     = *(const float4*)(ap + kt * 32);
    af[kt * 2 + 1] = *(const float4*)(ap + kt * 32 + 4);
  }

  // ---- phase 2: 16 rows x 128 cols, K=256 ----
  f32x4 acc[8];
  #pragma unroll
  for (int ct = 0; ct < 8; ++ct) acc[ct] = (f32x4){0.f, 0.f, 0.f, 0.f};
  float bcol[8];
  #pragma unroll
  for (int ct = 0; ct < 8; ++ct) bcol[ct] = bias[ct * 16 + l15];

  #pragma unroll
  for (int kt = 0; kt < 8; ++kt) {
    bf16x8 a;
    if (kt < 4) {                              // dst_feat (prefetched f32 -> bf16)
      float4 x = af[kt * 2], y = af[kt * 2 + 1];
      union { unsigned int u[4]; bf16x8 v; } cv;
      cv.u[0] = pk2(x.x, x.y); cv.u[1] = pk2(x.z, x.w);
      cv.u[2] = pk2(y.x, y.y); cv.u[3] = pk2(y.z, y.w);
      a = cv.v;
    } else {                                   // h from swizzled LDS
      int kb = (kt - 4) * 64 + lg * 16;
      a = *(const bf16x8*)(hrow + l15 * 256 + (kb ^ ((l15 & 7) << 4)));
    }
    bf16x8 b[8];
    #pragma unroll
    for (int ct = 0; ct < 8; ++ct)             // 1KB fully-coalesced fragment
      b[ct] = *(const bf16x8*)(wt + (((kt << 3) | ct) << 9) + (lane << 3));
    #pragma unroll
    for (int ct = 0; ct < 8; ++ct)
      acc[ct] = __builtin_amdgcn_mfma_f32_16x16x32_bf16(a, b[ct], acc[ct], 0, 0, 0);
  }

  // ---- epilogue: D layout col=lane&15, row=(lane>>4)*4+i ----
  #pragma unroll
  for (int i = 0; i < 4; ++i) {
    long row = e0 + lg * 4 + i;
    if (row < E) {
      float* op = out + row * 128 + l15;
      #pragma unroll
      for (int ct = 0; ct < 8; ++ct) op[ct * 16] = acc[ct][i] + bcol[ct];
    }
  }
}

extern "C" void kernel_launch(void* const* d_in, const int* in_sizes, int n_in,
                              void* d_out, int out_size, void* d_ws, size_t ws_size,
                              hipStream_t stream) {
  const float* src_feat = (const float*)d_in[0];
  const float* dst_feat = (const float*)d_in[1];
  const int*   dst      = (const int*)d_in[2];
  const float* W_self   = (const float*)d_in[3];
  const float* b_self   = (const float*)d_in[4];
  const float* W_neigh  = (const float*)d_in[5];
  const float* b_neigh  = (const float*)d_in[6];
  float* out = (float*)d_out;
  const int E = in_sizes[2];

  unsigned short* wt   = (unsigned short*)d_ws;           // 64KB repacked weights
  float*          bias = (float*)((char*)d_ws + 65536);   // 512B

  k_prep<<<128, 256, 0, stream>>>(W_self, W_neigh, b_self, b_neigh, wt, bias);

  int blocks = (E + 63) / 64;
  k_fused<<<blocks, 256, 0, stream>>>(src_feat, dst_feat, dst, wt, bias, out, E);
}

// Round 4
// 223.547 us; speedup vs baseline: 1.4497x; 1.0411x over previous
//
#include <hip/hip_runtime.h>

typedef float f32x4 __attribute__((ext_vector_type(4)));
typedef __bf16 bf16x8 __attribute__((ext_vector_type(8)));

typedef __attribute__((address_space(3))) unsigned char lds_u8;
typedef __attribute__((address_space(1))) const unsigned char g_u8c;

__device__ __forceinline__ unsigned short f2bf(float f) {
  unsigned int u = __float_as_uint(f);
  u += 0x7FFFu + ((u >> 16) & 1u);   // round-to-nearest-even
  return (unsigned short)(u >> 16);
}
__device__ __forceinline__ unsigned int pk2(float a, float b) {
  return (unsigned int)f2bf(a) | ((unsigned int)f2bf(b) << 16);
}
__device__ __forceinline__ void gload16(const void* g, void* l) {
  __builtin_amdgcn_global_load_lds((g_u8c*)g, (lds_u8*)l, 16, 0, 0);
}

// ---- Kernel 0: weights -> bf16, fragment-contiguous layout + bias sum ----
// b-fragment for (kt,ct) is 1KB contiguous: wt[(kt*8+ct)*512 + lane*8 + j],
// lane=lg*16+l15 maps to (n=ct*16+l15, k=kt*32+lg*8+j).
__global__ void k_prep(const float* __restrict__ Ws, const float* __restrict__ Wn,
                       const float* __restrict__ bs, const float* __restrict__ bn,
                       unsigned short* __restrict__ wt, float* __restrict__ bias) {
  int idx = blockIdx.x * 256 + threadIdx.x;   // 0..32767
  int n = idx >> 8, k = idx & 255;
  float v = (k < 128) ? Ws[k * 128 + n] : Wn[(k - 128) * 128 + n];
  int ct = n >> 4, l15 = n & 15, kt = k >> 5, lg = (k >> 3) & 3, j = k & 7;
  wt[(((kt << 3) | ct) << 9) + (((lg << 4) | l15) << 3) + j] = f2bf(v);
  if (idx < 128) bias[idx] = bs[idx] + bn[idx];
}

// ---- Fused: 1 wave per block, 16 rows, async LDS staging, zero barriers ----
__global__ __launch_bounds__(64, 2) void k_fused(
    const float* __restrict__ src, const float* __restrict__ dstf,
    const int* __restrict__ dst, const unsigned short* __restrict__ wt,
    const float* __restrict__ bias, float* __restrict__ out, int E)
{
  // ssrc rows: swizzled src f32 (512B/row); after scan consumes row r, its
  // phys bytes [0,256) are reused for the bf16 h row (same-wave DS order).
  __shared__ __align__(16) unsigned char ssrc[16 * 512];   // 8 KB
  __shared__ __align__(16) unsigned char sdst[16 * 512];   // 8 KB
  const int lane = threadIdx.x;                // 0..63
  const int l15 = lane & 15, lg = lane >> 4;
  const long e0 = (long)blockIdx.x * 16;
  const long emax = (long)E - 1;

  // ---- dst index loads first (feed ballot) ----
  long drow = e0 + l15; if (drow > emax) drow = emax;
  int myd = dst[drow];
  long back = e0 - 1 - lane;
  long backc = back < 0 ? 0 : back;
  int bd = dst[backc];

  // ---- async stage: 16 src rows then 16 dstf rows (1KB per issue) ----
  // phys[r*512 + (c ^ ((r&7)<<5))] = logical row r byte c  (rule #21: linear
  // LDS dest, inverse-swizzled global source).
  #pragma unroll
  for (int i = 0; i < 8; ++i) {
    int r2 = i * 2 + (lane >> 5);
    long gr = e0 + r2; if (gr > emax) gr = emax;
    int colb = ((lane & 31) << 4) ^ ((r2 & 7) << 5);
    gload16((const char*)src + gr * 512 + colb, ssrc + i * 1024);
  }
  #pragma unroll
  for (int i = 0; i < 8; ++i) {
    int r2 = i * 2 + (lane >> 5);
    long gr = e0 + r2; if (gr > emax) gr = emax;
    int colb = ((lane & 31) << 4) ^ ((r2 & 7) << 5);
    gload16((const char*)dstf + gr * 512 + colb, sdst + i * 1024);
  }

  // ---- bucket start via ballot (dst L2-resident: 2MB) ----
  int d0 = __shfl(myd, 0);
  unsigned long long m = __ballot((back >= 0) && (bd == d0));
  unsigned long long nm = ~m;
  int L = (nm == 0ull) ? 64 : __builtin_ctzll(nm);
  long s = e0 - L;
  while (s > 0 && dst[s - 1] == d0) --s;       // bucket >64 deep: ~never

  // ---- partial-bucket base sum from global (rows just staged nearby -> L2) ----
  float ax = 0.f, ay = 0.f;
  for (long e = s; e < e0; ++e) {
    float2 v = *(const float2*)(src + e * 128 + lane * 2);
    ax += v.x; ay += v.y;
  }

  // src rows staged (dstf may still be in flight)
  asm volatile("s_waitcnt vmcnt(8)" ::: "memory");

  // ---- cummean scan: read src row r from LDS, write h row r (bf16) over it ----
  int pos = (int)(e0 - s);
  int prevd = d0;
  #pragma unroll
  for (int r = 0; r < 16; ++r) {
    int d = __shfl(myd, r);
    if (d != prevd) { ax = 0.f; ay = 0.f; pos = 0; prevd = d; }
    float2 v = *(const float2*)(ssrc + r * 512 + ((lane * 8) ^ ((r & 7) << 5)));
    ax += v.x; ay += v.y;
    float inv = __builtin_amdgcn_rcpf((float)(pos + 1));
    *(unsigned int*)(ssrc + r * 512 + ((lane * 4) ^ ((r & 7) << 4))) = pk2(ax * inv, ay * inv);
    ++pos;
  }

  asm volatile("s_waitcnt lgkmcnt(0)" ::: "memory");   // h writes landed
  asm volatile("s_waitcnt vmcnt(0)" ::: "memory");     // dstf staged

  // ---- MFMA: 16 rows x 128 cols, K=256 ----
  f32x4 acc[8];
  #pragma unroll
  for (int ct = 0; ct < 8; ++ct) acc[ct] = (f32x4){0.f, 0.f, 0.f, 0.f};
  float bcol[8];
  #pragma unroll
  for (int ct = 0; ct < 8; ++ct) bcol[ct] = bias[ct * 16 + l15];

  #pragma unroll
  for (int kt = 0; kt < 8; ++kt) {
    bf16x8 a;
    if (kt < 4) {                              // dst_feat f32 from LDS -> bf16
      const unsigned char* p = sdst + l15 * 512 + ((kt * 128 + lg * 32) ^ ((l15 & 7) << 5));
      float4 x = *(const float4*)p;
      float4 y = *(const float4*)(p + 16);
      union { unsigned int u[4]; bf16x8 v; } cv;
      cv.u[0] = pk2(x.x, x.y); cv.u[1] = pk2(x.z, x.w);
      cv.u[2] = pk2(y.x, y.y); cv.u[3] = pk2(y.z, y.w);
      a = cv.v;
    } else {                                   // h bf16 from LDS (overlaid in ssrc)
      a = *(const bf16x8*)(ssrc + l15 * 512 + ((((kt - 4) * 64) + lg * 16) ^ ((l15 & 7) << 4)));
    }
    bf16x8 b[8];
    #pragma unroll
    for (int ct = 0; ct < 8; ++ct)             // 1KB fully-coalesced fragment (L2)
      b[ct] = *(const bf16x8*)(wt + (((kt << 3) | ct) << 9) + (lane << 3));
    #pragma unroll
    for (int ct = 0; ct < 8; ++ct)
      acc[ct] = __builtin_amdgcn_mfma_f32_16x16x32_bf16(a, b[ct], acc[ct], 0, 0, 0);
  }

  // ---- epilogue: D layout col=lane&15, row=(lane>>4)*4+i ----
  #pragma unroll
  for (int i = 0; i < 4; ++i) {
    long row = e0 + lg * 4 + i;
    if (row < E) {
      float* op = out + row * 128 + l15;
      #pragma unroll
      for (int ct = 0; ct < 8; ++ct) op[ct * 16] = acc[ct][i] + bcol[ct];
    }
  }
}

extern "C" void kernel_launch(void* const* d_in, const int* in_sizes, int n_in,
                              void* d_out, int out_size, void* d_ws, size_t ws_size,
                              hipStream_t stream) {
  const float* src_feat = (const float*)d_in[0];
  const float* dst_feat = (const float*)d_in[1];
  const int*   dst      = (const int*)d_in[2];
  const float* W_self   = (const float*)d_in[3];
  const float* b_self   = (const float*)d_in[4];
  const float* W_neigh  = (const float*)d_in[5];
  const float* b_neigh  = (const float*)d_in[6];
  float* out = (float*)d_out;
  const int E = in_sizes[2];

  unsigned short* wt   = (unsigned short*)d_ws;           // 64KB repacked weights
  float*          bias = (float*)((char*)d_ws + 65536);   // 512B

  k_prep<<<128, 256, 0, stream>>>(W_self, W_neigh, b_self, b_neigh, wt, bias);

  int blocks = (E + 15) / 16;
  k_fused<<<blocks, 64, 0, stream>>>(src_feat, dst_feat, dst, wt, bias, out, E);
}